// Round 6
// baseline (398.574 us; speedup 1.0000x reference)
//
#include <hip/hip_runtime.h>
#include <hip/hip_bf16.h>
#include <stdint.h>

#define NB 4096
#define ND 256
#define NC 32000
#define NCT (NC / 128)   // 250 col-tiles
#define BK 64

typedef __bf16 bf16x8 __attribute__((ext_vector_type(8)));
typedef float  f32x4  __attribute__((ext_vector_type(4)));

#define GLDS16(g, l)                                                          \
  __builtin_amdgcn_global_load_lds(                                           \
      (const __attribute__((address_space(1))) void*)(g),                     \
      (__attribute__((address_space(3))) void*)(l), 16, 0, 0)

__device__ __forceinline__ unsigned short f32_to_bf16(float f) {
  union { float f; uint32_t u; } v; v.f = f;
  uint32_t r = v.u + 0x7fffu + ((v.u >> 16) & 1u);
  return (unsigned short)(r >> 16);
}

// Cast inputs/V to bf16 in workspace; zero loss accumulator.
__global__ void prep_kernel(const float* __restrict__ inA,
                            const float* __restrict__ inV,
                            unsigned short* __restrict__ outA,
                            unsigned short* __restrict__ outV,
                            float* __restrict__ loss) {
  int gid = blockIdx.x * blockDim.x + threadIdx.x;
  int stride = gridDim.x * blockDim.x;
  if (gid == 0) *loss = 0.f;
  const int nA4 = NB * ND / 4;   // 262144
  const int nV4 = NC * ND / 4;   // 2048000
  for (int i = gid; i < nA4 + nV4; i += stride) {
    float4 v = (i < nA4) ? ((const float4*)inA)[i]
                         : ((const float4*)inV)[i - nA4];
    ushort4 o;
    o.x = f32_to_bf16(v.x);
    o.y = f32_to_bf16(v.y);
    o.z = f32_to_bf16(v.z);
    o.w = f32_to_bf16(v.w);
    if (i < nA4) ((ushort4*)outA)[i] = o;
    else         ((ushort4*)outV)[i - nA4] = o;
  }
}

// m97-style LDS-staged GEMM, adapted: 128x128 tile, BK=64 (4 K-steps),
// global_load_lds width-16 staging (no VGPR round-trip -> deep load pipe),
// XOR-swizzled LDS (pre-swizzled SOURCE + swizzled ds_read; LDS dest linear
// per rule #21) -> conflict-free ds_read_b128. Swapped-operand MFMA so each
// lane's acc regs = 4 consecutive out cols -> direct NT float4 stores.
// exp-rowsums via LDS -> per-col-tile partial array (no atomics).
__global__ void __launch_bounds__(256, 3)
gemm_expsum_kernel(const unsigned short* __restrict__ A,
                   const unsigned short* __restrict__ V,
                   float* __restrict__ out,       // d_out + 1
                   float* __restrict__ partial) { // [NCT][NB]
  __shared__ unsigned short As[128 * BK];   // 16 KB, row-major 128B/row, swizzled
  __shared__ unsigned short Vs[128 * BK];   // 16 KB
  __shared__ float red[2][128];

  const int b = blockIdx.x;
  const int xcd = b & 7;
  const int s = b >> 3;                     // 0..1023 per XCD
  const int colt = (xcd << 5) + (s & 31);   // 32 col-tiles per XCD, col-fast
  const int rowt = s >> 5;                  // 0..31
  if (colt >= NCT) return;                  // padded tail (colt 250..255)
  const int brow = rowt << 7;
  const int bcol = colt << 7;

  const int tid  = threadIdx.x;
  const int lane = tid & 63;
  const int wave = tid >> 6;
  const int wr   = wave >> 1;
  const int wc   = wave & 1;
  const int c16  = lane & 15;
  const int kq   = lane >> 4;      // 0..3

  const char* Ab = (const char*)A;
  const char* Vb = (const char*)V;

  // Staging plan per K-step: 128 rows x 128B = 1024 chunks of 16B per matrix;
  // thread t takes chunks {i*256+t}. LDS dest is LINEAR (chunk*16); the
  // global source fetches group g = sg ^ (row&7) so that LDS slot (row,sg)
  // holds global group sg^(row&7)  (XOR involution, matches read side).
  int srow[4], sgrp[4];
#pragma unroll
  for (int i = 0; i < 4; ++i) {
    const int chunk = i * 256 + tid;
    srow[i] = chunk >> 3;
    sgrp[i] = (chunk & 7) ^ (srow[i] & 7);
  }

  f32x4 acc[4][4];   // acc[c][r]: c = V-frag (out cols), r = A-frag (out rows)
#pragma unroll
  for (int c = 0; c < 4; ++c)
#pragma unroll
    for (int r = 0; r < 4; ++r)
      acc[c][r] = (f32x4){0.f, 0.f, 0.f, 0.f};

  for (int kt = 0; kt < ND / BK; ++kt) {
    const int kb = kt * (BK * 2);   // byte offset into a 512B K-row
#pragma unroll
    for (int i = 0; i < 4; ++i) {
      char* ldst = (char*)As + (i * 256 + wave * 64) * 16;  // wave-uniform
      GLDS16(Ab + (size_t)(brow + srow[i]) * 512 + kb + sgrp[i] * 16, ldst);
    }
#pragma unroll
    for (int i = 0; i < 4; ++i) {
      char* ldst = (char*)Vs + (i * 256 + wave * 64) * 16;
      GLDS16(Vb + (size_t)(bcol + srow[i]) * 512 + kb + sgrp[i] * 16, ldst);
    }
    __syncthreads();   // vmcnt(0) drain + barrier: tiles ready

    // Fragments: row-major [128][BK], swizzled group index.
    bf16x8 af[4][2], vf[4][2];
#pragma unroll
    for (int m = 0; m < 4; ++m) {
      const int arow = wr * 64 + m * 16 + c16;
      const int vrow = wc * 64 + m * 16 + c16;
#pragma unroll
      for (int ks = 0; ks < 2; ++ks) {
        const int g = ks * 4 + kq;
        af[m][ks] = *(const bf16x8*)((const char*)As + arow * 128 +
                                     ((g ^ (arow & 7)) * 16));
        vf[m][ks] = *(const bf16x8*)((const char*)Vs + vrow * 128 +
                                     ((g ^ (vrow & 7)) * 16));
      }
    }
#pragma unroll
    for (int ks = 0; ks < 2; ++ks)
#pragma unroll
      for (int c = 0; c < 4; ++c)
#pragma unroll
        for (int r = 0; r < 4; ++r)
          acc[c][r] = __builtin_amdgcn_mfma_f32_16x16x32_bf16(
              vf[c][ks], af[r][ks], acc[c][r], 0, 0, 0);
    __syncthreads();   // protect LDS before next stage overwrites
  }

  // Epilogue: direct NT float4 stores + exp-rowsum (no atomics).
  // acc[c][r] reg q -> out[brow+wr*64+r*16+c16][bcol+wc*64+c*16+kq*4+q]
#pragma unroll
  for (int r = 0; r < 4; ++r) {
    const int grow = brow + wr * 64 + r * 16 + c16;
    float* prow = out + (size_t)grow * NC + (bcol + wc * 64 + kq * 4);
    float sum = 0.f;
#pragma unroll
    for (int c = 0; c < 4; ++c) {
      f32x4 v = acc[c][r];
      __builtin_nontemporal_store(v, (f32x4*)(prow + c * 16));
      sum += __expf(v[0]) + __expf(v[1]) + __expf(v[2]) + __expf(v[3]);
    }
    sum += __shfl_xor(sum, 16);
    sum += __shfl_xor(sum, 32);
    if (lane < 16) red[wc][wr * 64 + r * 16 + c16] = sum;
  }
  __syncthreads();
  if (tid < 128)
    partial[(size_t)colt * NB + brow + tid] = red[0][tid] + red[1][tid];
}

// loss = mean_r( log(sum_c partial[c][r]) - out[r, targets[r]] )
__global__ void finalize_kernel(const float* __restrict__ partial,
                                const float* __restrict__ out,  // d_out + 1
                                const int* __restrict__ targets,
                                float* __restrict__ loss) {
  int r = blockIdx.x * blockDim.x + threadIdx.x;   // 0..NB-1
  float s = 0.f;
  for (int c = 0; c < NCT; ++c) s += partial[(size_t)c * NB + r];
  float li = logf(s) - out[(size_t)r * NC + targets[r]];
#pragma unroll
  for (int o = 32; o > 0; o >>= 1) li += __shfl_down(li, o);
  __shared__ float wsum[4];
  int lane = threadIdx.x & 63, wv = threadIdx.x >> 6;
  if (lane == 0) wsum[wv] = li;
  __syncthreads();
  if (threadIdx.x == 0) {
    float bs = wsum[0] + wsum[1] + wsum[2] + wsum[3];
    atomicAdd(loss, bs * (1.0f / NB));
  }
}

extern "C" void kernel_launch(void* const* d_in, const int* in_sizes, int n_in,
                              void* d_out, int out_size, void* d_ws, size_t ws_size,
                              hipStream_t stream) {
  const float* inputs  = (const float*)d_in[0];
  const int*   targets = (const int*)d_in[1];
  // d_in[2] indexs, d_in[3] label_to_pairs, d_in[4] all_label_to_clusterid: unused (W_MS = 0)
  const float* V       = (const float*)d_in[5];

  float* loss    = (float*)d_out;          // output 0: scalar loss
  float* outputs = (float*)d_out + 1;      // output 1: [4096][32000]

  char* ws = (char*)d_ws;
  unsigned short* Abf = (unsigned short*)ws;                              // 2 MB
  unsigned short* Vbf = (unsigned short*)(ws + (size_t)NB * ND * 2);      // 16.4 MB
  float* partial = (float*)(ws + (size_t)NB * ND * 2 + (size_t)NC * ND * 2); // 3.9 MB

  hipLaunchKernelGGL(prep_kernel, dim3(2048), dim3(256), 0, stream,
                     inputs, V, Abf, Vbf, loss);
  // grid: 8 XCDs x 1024 (32 col-tiles x 32 row-tiles), col-tiles padded to 256
  hipLaunchKernelGGL(gemm_expsum_kernel, dim3(8 * 1024), dim3(256), 0, stream,
                     Abf, Vbf, outputs, partial);
  hipLaunchKernelGGL(finalize_kernel, dim3(NB / 256), dim3(256), 0, stream,
                     partial, outputs, targets, loss);
}